// Round 16
// baseline (161.326 us; speedup 1.0000x reference)
//
#include <hip/hip_runtime.h>

#define NB 8
#define NS 2048
#define ND 64
#define LOG2E 1.44269504f
#define SP 76                  // LDS row stride in halfs (152B = 38 dwords, conflict-free)
#define KBUF (64 * SP)         // one K/V tile buffer (halfs)

typedef _Float16 half8 __attribute__((ext_vector_type(8)));
typedef _Float16 half4 __attribute__((ext_vector_type(4)));
typedef __attribute__((ext_vector_type(4))) float floatx4;

__device__ __forceinline__ half8 cvt8(const float* p) {
    float4 a = *(const float4*)p;
    float4 b = *(const float4*)(p + 4);
    half8 h = {(_Float16)a.x, (_Float16)a.y, (_Float16)a.z, (_Float16)a.w,
               (_Float16)b.x, (_Float16)b.y, (_Float16)b.z, (_Float16)b.w};
    return h;
}
__device__ __forceinline__ half8 cvtWcol(const float* base) {
    half8 h;
#pragma unroll
    for (int j = 0; j < 8; ++j) h[j] = (_Float16)base[j * 64];
    return h;
}

// ---------------- QKV projection via fp16 MFMA (r9 verbatim; XCD-aligned) -----
__global__ __launch_bounds__(256) void qkv_proj(
    const float* __restrict__ x,
    const float* __restrict__ Wq, const float* __restrict__ bq,
    const float* __restrict__ Wk, const float* __restrict__ bk,
    const float* __restrict__ Wv, const float* __restrict__ bv,
    _Float16* __restrict__ Qg, _Float16* __restrict__ Kg,
    _Float16* __restrict__ Vt)
{
    __shared__ _Float16 vt[64 * 18];

    const int tid  = threadIdx.x;
    const int wv   = tid >> 6;
    const int l    = tid & 63;
    const int quad = l >> 4;
    const int tx   = l & 15;

    const int b  = blockIdx.x & 7;
    const int n0 = (blockIdx.x >> 3) * 16;

    const float* xr = x + ((size_t)b * NS + n0 + tx) * ND + quad * 8;
    half8 a0 = cvt8(xr);
    half8 a1 = cvt8(xr + 32);

    const floatx4 zf = {0.f, 0.f, 0.f, 0.f};

#pragma unroll
    for (int i = 0; i < 3; ++i) {
        const int ct = wv * 3 + i;
        const int m  = ct >> 2;
        const int lcol = (ct & 3) * 16 + tx;

        const float* Wm;
        const float* Bm;
        if (m == 0)      { Wm = Wq; Bm = bq; }
        else if (m == 1) { Wm = Wk; Bm = bk; }
        else             { Wm = Wv; Bm = bv; }

        half8 b0 = cvtWcol(Wm + (quad * 8) * 64 + lcol);
        half8 b1 = cvtWcol(Wm + (32 + quad * 8) * 64 + lcol);

        floatx4 acc = __builtin_amdgcn_mfma_f32_16x16x32_f16(a0, b0, zf, 0, 0, 0);
        acc = __builtin_amdgcn_mfma_f32_16x16x32_f16(a1, b1, acc, 0, 0, 0);
        const float bias = Bm[lcol];

        if (m == 0) {
#pragma unroll
            for (int r = 0; r < 4; ++r)
                Qg[((size_t)b * NS + n0 + quad * 4 + r) * ND + lcol] =
                    (_Float16)((acc[r] + bias) * LOG2E);
        } else if (m == 1) {
#pragma unroll
            for (int r = 0; r < 4; ++r)
                Kg[((size_t)b * NS + n0 + quad * 4 + r) * ND + lcol] = (_Float16)(acc[r] + bias);
        } else {
#pragma unroll
            for (int r = 0; r < 4; ++r)
                vt[lcol * 18 + quad * 4 + r] = (_Float16)(acc[r] + bias);
        }
    }
    __syncthreads();
    {
        const int d = tid >> 2, seg = tid & 3;
        uint2 p = *(uint2*)&vt[d * 18 + seg * 4];
        *(uint2*)(Vt + ((size_t)b * ND + d) * NS + n0 + seg * 4) = p;
    }
}

// ---------------- fused masked attention: S^T trick, no P round-trip ---------
// grid: 512 blocks (b = blk&7 XCD-pinned, 32 q-rows), 512 thr = 8 waves =
// 2 q-halves (h) x 4 key-quarters (kq: 16 keys/tile). K/V double-buffered LDS.
// S^T = K·Q^T (swap MFMA operands): lane holds S^T[key=quad*4+r][qrow=tx],
// which IS the B-operand layout of mfma_f32_16x16x16f16 — masked P goes from
// registers straight into PV (O^T = V^T·P). No psm, one barrier per tile.
// Pass 1: l = sum 2^s. Mask: e > l/N <=> p > mean(p) = 1/N.
__global__ __launch_bounds__(512, 2) void attn(
    const _Float16* __restrict__ Qg,
    const _Float16* __restrict__ Kg,
    const _Float16* __restrict__ Vt,
    float* __restrict__ out)
{
    // ksm: 2 bufs [key][SP]; vsm: 2 bufs [dim][SP]; obuf (union, used after loops)
    __shared__ __align__(16) _Float16 smraw[4 * KBUF];   // 38912 B
    __shared__ float lsh[128];
    _Float16* ksm = smraw;
    _Float16* vsm = smraw + 2 * KBUF;
    float*    obuf = (float*)smraw;                      // 8 x 16 x 68 fp32 = 34816 B

    const int tid  = threadIdx.x;
    const int wv   = tid >> 6;
    const int l    = tid & 63;
    const int quad = l >> 4;
    const int tx   = l & 15;
    const int h    = wv >> 2;       // q-half (16 rows)
    const int kq   = wv & 3;        // key-quarter (16 keys per tile)

    const int b  = blockIdx.x & 7;
    const int q0 = (blockIdx.x >> 3) * 32;

    const _Float16* Qb = Qg + ((size_t)b * NS + q0 + h * 16) * ND;
    const _Float16* Kb = Kg + (size_t)b * NS * ND;
    const _Float16* Vb = Vt + (size_t)b * ND * NS;

    // Q as B-operand: lane tx -> qrow h*16+tx, k = d = quad*8+j (chunks 0/1)
    half8 qf0 = *(const half8*)(Qb + (size_t)tx * ND + quad * 8);
    half8 qf1 = *(const half8*)(Qb + (size_t)tx * ND + 32 + quad * 8);

    // staging roles: thread -> 16B of the 8KB tile
    const int skey = tid >> 3;              // key (K) or dim (V)
    const int sc   = (tid & 7) * 8;
    const _Float16* Ksrc = Kb + (size_t)skey * ND + sc;   // + t*64*ND
    const _Float16* Vsrc = Vb + (size_t)skey * NS + sc;   // + t*64
    const int sdst = skey * SP + sc;

    const floatx4 zf = {0.f, 0.f, 0.f, 0.f};
    const int krow = (kq * 16 + tx) * SP;   // K A-frag row base (key = kq*16+tx)

    // ================= pass 1: l = sum 2^s =================
    float lacc = 0.f;
    {
        uint4 gk = *(const uint4*)Ksrc;            // tile 0
        *(uint4*)(ksm + sdst) = gk;
        for (int t = 0; t < 32; ++t) {
            const _Float16* kb_ = ksm + (t & 1) * KBUF;
            __syncthreads();                        // tile t staged & visible
            if (t < 31) gk = *(const uint4*)(Ksrc + (size_t)(t + 1) * 64 * ND);
            half8 kf0 = *(const half8*)(kb_ + krow + quad * 8);
            half8 kf1 = *(const half8*)(kb_ + krow + 32 + quad * 8);
            // S^T = K·Q^T : A = kf (m=key), B = qf (n=qrow)
            floatx4 c = __builtin_amdgcn_mfma_f32_16x16x32_f16(kf0, qf0, zf, 0, 0, 0);
            c = __builtin_amdgcn_mfma_f32_16x16x32_f16(kf1, qf1, c, 0, 0, 0);
            lacc += __builtin_amdgcn_exp2f(c[0]) + __builtin_amdgcn_exp2f(c[1])
                  + __builtin_amdgcn_exp2f(c[2]) + __builtin_amdgcn_exp2f(c[3]);
            if (t < 31) *(uint4*)(ksm + ((t & 1) ^ 1) * KBUF + sdst) = gk;
        }
    }
    // lane holds partial l for qrow=tx over its 4-key rows: reduce across quads
    lacc += __shfl_xor(lacc, 16);
    lacc += __shfl_xor(lacc, 32);
    if (l < 16) lsh[wv * 16 + l] = lacc;

    // pass-2 tile-0 loads overlap the merge barrier
    uint4 gk2 = *(const uint4*)Ksrc;
    uint4 gv  = *(const uint4*)Vsrc;
    __syncthreads();                                // lsh ready; pass-1 LDS reads done

    float L = lsh[(h * 4 + 0) * 16 + tx] + lsh[(h * 4 + 1) * 16 + tx]
            + lsh[(h * 4 + 2) * 16 + tx] + lsh[(h * 4 + 3) * 16 + tx];
    const float inv = 1.f / L;
    const float thr = L * (1.f / (float)NS);

    // ================= pass 2: S^T -> mask -> PV (registers only) =================
    *(uint4*)(ksm + sdst) = gk2;
    *(uint4*)(vsm + sdst) = gv;
    floatx4 o[4] = {zf, zf, zf, zf};                // O^T[dim-tile dt][qrow=tx]

    for (int t = 0; t < 32; ++t) {
        const _Float16* kb_ = ksm + (t & 1) * KBUF;
        const _Float16* vb_ = vsm + (t & 1) * KBUF;
        __syncthreads();                            // tiles staged & visible
        if (t < 31) {
            gk2 = *(const uint4*)(Ksrc + (size_t)(t + 1) * 64 * ND);
            gv  = *(const uint4*)(Vsrc + (size_t)(t + 1) * 64);
        }
        half8 kf0 = *(const half8*)(kb_ + krow + quad * 8);
        half8 kf1 = *(const half8*)(kb_ + krow + 32 + quad * 8);
        floatx4 c = __builtin_amdgcn_mfma_f32_16x16x32_f16(kf0, qf0, zf, 0, 0, 0);
        c = __builtin_amdgcn_mfma_f32_16x16x32_f16(kf1, qf1, c, 0, 0, 0);
        // masked P in B-operand layout of 16x16x16 (k=key=quad*4+r, n=qrow=tx)
        half4 w;
#pragma unroll
        for (int r = 0; r < 4; ++r) {
            float e = __builtin_amdgcn_exp2f(c[r]);
            w[r] = (e > thr) ? (_Float16)(e * inv) : (_Float16)0.f;
        }
        // PV: O^T += V^T·P ; A = V^T frag (m=dim=dt*16+tx, k=key=quad*4+j)
#pragma unroll
        for (int dt = 0; dt < 4; ++dt) {
            half4 vf = *(const half4*)(vb_ + (dt * 16 + tx) * SP + kq * 16 + quad * 4);
            o[dt] = __builtin_amdgcn_mfma_f32_16x16x16f16(vf, w, o[dt], 0, 0, 0);
        }
        if (t < 31) {
            *(uint4*)(ksm + ((t & 1) ^ 1) * KBUF + sdst) = gk2;
            *(uint4*)(vsm + ((t & 1) ^ 1) * KBUF + sdst) = gv;
        }
    }

    __syncthreads();   // all ksm/vsm reads complete before obuf reuse
    // lane (quad,tx) holds O[qrow=h*16+tx][dim=dt*16+quad*4+r] -> obuf per wave
#pragma unroll
    for (int dt = 0; dt < 4; ++dt)
        *(floatx4*)(obuf + wv * (16 * 68) + tx * 68 + dt * 16 + quad * 4) = o[dt];
    __syncthreads();

    {   // merge the 4 key-quarters, store
        const int row = tid >> 4;            // 0..31
        const int c4  = (tid & 15) * 4;
        const int hh  = row >> 4, rl = row & 15;
        float4 s = {0.f, 0.f, 0.f, 0.f};
#pragma unroll
        for (int k2 = 0; k2 < 4; ++k2) {
            float4 v = *(float4*)(obuf + ((hh * 4 + k2) * 16 + rl) * 68 + c4);
            s.x += v.x; s.y += v.y; s.z += v.z; s.w += v.w;
        }
        *(float4*)(out + ((size_t)b * NS + q0 + row) * ND + c4) = s;
    }
}

extern "C" void kernel_launch(void* const* d_in, const int* in_sizes, int n_in,
                              void* d_out, int out_size, void* d_ws, size_t ws_size,
                              hipStream_t stream) {
    const float* x  = (const float*)d_in[0];
    const float* Wq = (const float*)d_in[1];
    const float* bq = (const float*)d_in[2];
    const float* Wk = (const float*)d_in[3];
    const float* bk = (const float*)d_in[4];
    const float* Wv = (const float*)d_in[5];
    const float* bv = (const float*)d_in[6];

    _Float16* Qg = (_Float16*)d_ws;
    _Float16* Kg = Qg + (size_t)NB * NS * ND;
    _Float16* Vt = Kg + (size_t)NB * NS * ND;

    qkv_proj<<<NB * (NS / 16), 256, 0, stream>>>(x, Wq, bq, Wk, bk, Wv, bv, Qg, Kg, Vt);
    attn<<<NB * (NS / 32), 512, 0, stream>>>(Qg, Kg, Vt, (float*)d_out);
}